// Round 7
// baseline (142.174 us; speedup 1.0000x reference)
//
#include <hip/hip_runtime.h>
#include <hip/hip_bf16.h>
#include <math.h>

// Problem constants (AttentionSynapse): B=2, Tq=Tk=2048, E=Eq=Ek=1024, H=16, D=64
#define B_    2
#define TQ    2048
#define TK    2048
#define E_    1024
#define MTOT  4096   // B*TQ

typedef __attribute__((ext_vector_type(8))) short bf16x8;
typedef __attribute__((ext_vector_type(4))) float f32x4;

__device__ __forceinline__ unsigned short f2bf(float x) {
  unsigned int u = __float_as_uint(x);
  u += 0x7fff + ((u >> 16) & 1);      // round-to-nearest-even
  return (unsigned short)(u >> 16);
}

__device__ __forceinline__ void load_lds16(const void* g, void* l) {
  // async global->LDS, 16B/lane; LDS dest = wave-uniform base + lane*16
  __builtin_amdgcn_global_load_lds(
      (const __attribute__((address_space(1))) unsigned int*)g,
      (__attribute__((address_space(3))) unsigned int*)l, 16, 0, 0);
}

#define BARRIER() do { asm volatile("" ::: "memory"); __builtin_amdgcn_s_barrier(); asm volatile("" ::: "memory"); } while (0)
#define WAIT_VM4()   asm volatile("s_waitcnt vmcnt(4)" ::: "memory")
#define WAIT_VM0()   asm volatile("s_waitcnt vmcnt(0)" ::: "memory")

// ---------------------------------------------------------------------------
// T2 swizzle: logical (row, byte o in 0..127) lives at LDS byte
//   row*128 + (o ^ ((row&7)<<4)).
// LDS write is linear (gload_lds: base + tid*16); the GLOBAL source column is
// pre-permuted with the same involutive XOR; ds_read applies the XOR (rule #21).
// ---------------------------------------------------------------------------

// A-tile: 256 rows x 64 cols bf16 (32 KiB), 512 threads x 4 loads.
__device__ __forceinline__ void stage_A(const unsigned short* gsrc, unsigned short* lds,
                                        int tid, int kt) {
  const int r  = tid >> 3;                          // 0..63
  const int c8 = ((tid & 7) ^ (r & 7)) * 8;         // pre-swizzled col (elems)
  const unsigned short* g = gsrc + (size_t)r * E_ + (size_t)kt * 64 + c8;
  unsigned short* l = lds + tid * 8;
#pragma unroll
  for (int i = 0; i < 4; ++i)                       // rows r, r+64, r+128, r+192
    load_lds16(g + (size_t)(64 * i) * E_, l + 4096 * i);
}
// B-tile: 128 rows x 64 cols bf16 (16 KiB), 512 threads x 2 loads.
__device__ __forceinline__ void stage_B(const unsigned short* gsrc, unsigned short* lds,
                                        int tid, int kt) {
  const int r  = tid >> 3;
  const int c8 = ((tid & 7) ^ (r & 7)) * 8;
  const unsigned short* g = gsrc + (size_t)r * E_ + (size_t)kt * 64 + c8;
  unsigned short* l = lds + tid * 8;
#pragma unroll
  for (int i = 0; i < 2; ++i)                       // rows r, r+64
    load_lds16(g + (size_t)(64 * i) * E_, l + 4096 * i);
}

// Swizzled LDS read address (elems): row in tile, o = byte offset in row
#define LDS_AT(base, row, o) ((const bf16x8*)((base) + (((row) * 128 + ((o) ^ (((row) & 7) << 4))) >> 1)))

#define READ_A_ALL()                                                          \
  do {                                                                        \
    _Pragma("unroll") for (int f = 0; f < 4; ++f)                             \
      _Pragma("unroll") for (int ks = 0; ks < 2; ++ks)                        \
        a[f][ks] = *LDS_AT(Ac, wm * 64 + f * 16 + li16, ks * 64 + hi4 * 16);  \
  } while (0)

#define READ_B(g0)                                                            \
  do {                                                                        \
    _Pragma("unroll") for (int g = (g0); g < (g0) + 2; ++g)                   \
      _Pragma("unroll") for (int ks = 0; ks < 2; ++ks)                        \
        b[g][ks] = *LDS_AT(Bc, wn * 64 + g * 16 + li16, ks * 64 + hi4 * 16);  \
  } while (0)

#define MFMA_HALF(g0)                                                         \
  do {                                                                        \
    __builtin_amdgcn_s_setprio(1);                                            \
    _Pragma("unroll") for (int ks = 0; ks < 2; ++ks)                          \
      _Pragma("unroll") for (int f = 0; f < 4; ++f)                           \
        _Pragma("unroll") for (int g = (g0); g < (g0) + 2; ++g)               \
          acc[f][g] = __builtin_amdgcn_mfma_f32_16x16x32_bf16(                \
              a[f][ks], b[g][ks], acc[f][g], 0, 0, 0);                        \
    __builtin_amdgcn_s_setprio(0);                                            \
  } while (0)

// 256x128 tile, BK=64, 8 waves (4M x 2N), per-wave C = 64x64, NT=16 K-tiles.
// A on a 3-slot ring, B on 2 slots: staging NEVER targets a slot read by the
// current tile, so ONE barrier per K-tile suffices and LDS-reads/MFMA of
// different waves overlap freely. vmcnt(4) per tile (counted, never 0):
// wave-local history at tile-t end (new->old): A(t+2)[4], B(t+1)[2], A(t+1)[4]
// -> wait<=4 drains A(t+1)+B(t+1) exactly. Barrier then makes it collective.
#define GEMM_PIPELINE()                                                       \
  do {                                                                        \
    stage_A(Ag, Asl[0], tid, 0);                                              \
    stage_B(Bg, Bsl[0], tid, 0);                                              \
    stage_A(Ag, Asl[1], tid, 1);                                              \
    WAIT_VM4();    /* drains A(0)+B(0); A(1) stays in flight */               \
    int s0 = 0, s2 = 2;   /* t%3, (t+2)%3 */                                  \
    for (int t = 0; t < 16; ++t) {                                            \
      BARRIER();                                                              \
      const unsigned short* Ac = Asl[s0];                                     \
      const unsigned short* Bc = Bsl[t & 1];                                  \
      /* q0: left C-half */                                                   \
      READ_A_ALL(); READ_B(0);                                                \
      stage_B(Bg, Bsl[(t + 1) & 1], tid, (t + 1) & 15);                       \
      MFMA_HALF(0);                                                           \
      /* q1: right C-half */                                                  \
      READ_B(2);                                                              \
      stage_A(Ag, Asl[s2], tid, (t + 2) & 15);                                \
      MFMA_HALF(2);                                                           \
      WAIT_VM4();                                                             \
      s0 = (s0 == 2) ? 0 : s0 + 1;                                            \
      s2 = (s2 == 2) ? 0 : s2 + 1;                                            \
    }                                                                         \
  } while (0)

// ---------------------------------------------------------------------------
// prep: bf16-cast gq, gk, WK; scale WQ rows by Wmix[head] then cast.
// ---------------------------------------------------------------------------
__global__ void prep_kernel(const float* __restrict__ gq, const float* __restrict__ gk,
                            const float* __restrict__ WQ, const float* __restrict__ WK,
                            const float* __restrict__ Wmix,
                            unsigned short* __restrict__ gqb, unsigned short* __restrict__ gkb,
                            unsigned short* __restrict__ wqb, unsigned short* __restrict__ wkb) {
  const int NGQ = (B_ * TQ * E_) / 4;   // 1048576 vec4
  const int NW  = (E_ * E_) / 4;        // 262144 vec4
  const int total = 2 * NGQ + 2 * NW;
  for (int idx = blockIdx.x * blockDim.x + threadIdx.x; idx < total;
       idx += gridDim.x * blockDim.x) {
    const float4* src; unsigned short* dst; int local; float scale = 1.0f;
    if (idx < NGQ)            { src = (const float4*)gq; dst = gqb; local = idx; }
    else if (idx < 2 * NGQ)   { src = (const float4*)gk; dst = gkb; local = idx - NGQ; }
    else if (idx < 2*NGQ+NW)  { src = (const float4*)WQ; dst = wqb; local = idx - 2*NGQ;
                                scale = Wmix[local >> 14]; }   // vec4 idx -> row e = local/256, head = e/64
    else                      { src = (const float4*)WK; dst = wkb; local = idx - 2*NGQ - NW; }
    float4 v = src[local];
    ushort4 o;
    o.x = f2bf(v.x * scale); o.y = f2bf(v.y * scale);
    o.z = f2bf(v.z * scale); o.w = f2bf(v.w * scale);
    ((ushort4*)dst)[local] = o;
  }
}

// ---------------------------------------------------------------------------
// Projection GEMM: C[m,n] = sum_k A[m,k]*W[n,k]. 256x128 tile, 1 block/CU.
// grid = (8 n-tiles, 16 m-tiles, 2 sides) = 256 blocks.
// ---------------------------------------------------------------------------
__global__ __launch_bounds__(512, 2) void proj_kernel(
    const unsigned short* __restrict__ gqb, const unsigned short* __restrict__ gkb,
    const unsigned short* __restrict__ wqb, const unsigned short* __restrict__ wkb,
    unsigned short* __restrict__ qp, unsigned short* __restrict__ kp) {
  __shared__ __align__(16) unsigned short Asl[3][16384];   // 3 x (256x64)
  __shared__ __align__(16) unsigned short Bsl[2][8192];    // 2 x (128x64)
  const int m0 = blockIdx.y * 256, n0 = blockIdx.x * 128;
  const unsigned short* Ag = (blockIdx.z ? gkb : gqb) + (size_t)m0 * E_;
  const unsigned short* Bg = (blockIdx.z ? wkb : wqb) + (size_t)n0 * E_;
  unsigned short* C        = (blockIdx.z ? kp  : qp);
  const int tid = threadIdx.x, wave = tid >> 6, lane = tid & 63;
  const int wm = wave >> 1, wn = wave & 1, li16 = lane & 15, hi4 = lane >> 4;
  f32x4 acc[4][4] = {};
  bf16x8 a[4][2];
  bf16x8 b[4][2];
  GEMM_PIPELINE();
#pragma unroll
  for (int f = 0; f < 4; ++f)
#pragma unroll
    for (int g = 0; g < 4; ++g)
#pragma unroll
      for (int j = 0; j < 4; ++j) {
        int row = m0 + wm * 64 + f * 16 + hi4 * 4 + j;
        int col = n0 + wn * 64 + g * 16 + li16;
        C[(size_t)row * E_ + col] = f2bf(acc[f][g][j]);
      }
  WAIT_VM0();   // drain wrapped tail stages before endpgm
}

// ---------------------------------------------------------------------------
// Score GEMM + fused partial logsumexp. 256x128 tile, 1 block/CU.
// grid = (16 k-tiles, 8 q-tiles, 2 batches) = 256 blocks; partials stride 16.
// ---------------------------------------------------------------------------
__global__ __launch_bounds__(512, 2) void score_lse_kernel(
    const unsigned short* __restrict__ qp, const unsigned short* __restrict__ kp,
    float2* __restrict__ partials) {
  __shared__ __align__(16) unsigned short Asl[3][16384];
  __shared__ __align__(16) unsigned short Bsl[2][8192];
  __shared__ float redM[2][256];
  __shared__ float redS[2][256];
  const int bb = blockIdx.z;
  const int m0 = blockIdx.y * 256, n0 = blockIdx.x * 128;
  const unsigned short* Ag = qp + (size_t)bb * TQ * E_ + (size_t)m0 * E_;
  const unsigned short* Bg = kp + (size_t)bb * TK * E_ + (size_t)n0 * E_;
  const int tid = threadIdx.x, wave = tid >> 6, lane = tid & 63;
  const int wm = wave >> 1, wn = wave & 1, li16 = lane & 15, hi4 = lane >> 4;
  f32x4 acc[4][4] = {};
  bf16x8 a[4][2];
  bf16x8 b[4][2];
  GEMM_PIPELINE();
  // ---- per-row LSE partial over this block's 128 cols ----
  // lane holds rows wm*64 + f*16 + hi4*4 + j ; cols wn*64 + g*16 + li16
#pragma unroll
  for (int f = 0; f < 4; ++f) {
#pragma unroll
    for (int j = 0; j < 4; ++j) {
      float m = fmaxf(fmaxf(acc[f][0][j], acc[f][1][j]),
                      fmaxf(acc[f][2][j], acc[f][3][j]));
#pragma unroll
      for (int msk = 1; msk < 16; msk <<= 1) m = fmaxf(m, __shfl_xor(m, msk, 64));
      float s = 0.f;
#pragma unroll
      for (int g = 0; g < 4; ++g) s += expf(acc[f][g][j] - m);
#pragma unroll
      for (int msk = 1; msk < 16; msk <<= 1) s += __shfl_xor(s, msk, 64);
      if (li16 == 0) {
        int row = wm * 64 + f * 16 + hi4 * 4 + j;   // 0..255 unique per (wm,f,hi4,j)
        redM[wn][row] = m;
        redS[wn][row] = s;
      }
    }
  }
  __syncthreads();   // drains pending tail stages + makes red[] visible
  if (tid < 256) {
    float mA = redM[0][tid], mB = redM[1][tid];
    float M = fmaxf(mA, mB);
    float S = redS[0][tid] * expf(mA - M) + redS[1][tid] * expf(mB - M);
    int qrow = bb * TQ + m0 + tid;
    partials[(size_t)qrow * 16 + blockIdx.x] = make_float2(M, S);
  }
}

// ---------------------------------------------------------------------------
// finalize: combine 16 (m,s) partials per q-row -> logsumexp
// ---------------------------------------------------------------------------
__global__ void finalize_kernel(const float2* __restrict__ partials, float* __restrict__ out) {
  int r = blockIdx.x * blockDim.x + threadIdx.x;
  if (r >= MTOT) return;
  const float2* p = partials + (size_t)r * 16;
  float M = p[0].x;
#pragma unroll
  for (int i = 1; i < 16; ++i) M = fmaxf(M, p[i].x);
  float S = 0.f;
#pragma unroll
  for (int i = 0; i < 16; ++i) S += p[i].y * expf(p[i].x - M);
  out[r] = logf(S) + M;
}

// ---------------------------------------------------------------------------
extern "C" void kernel_launch(void* const* d_in, const int* in_sizes, int n_in,
                              void* d_out, int out_size, void* d_ws, size_t ws_size,
                              hipStream_t stream) {
  const float* gq   = (const float*)d_in[0];
  const float* gk   = (const float*)d_in[1];
  const float* WQ   = (const float*)d_in[2];
  const float* WK   = (const float*)d_in[3];
  const float* Wmix = (const float*)d_in[4];
  float* out = (float*)d_out;

  char* ws = (char*)d_ws;
  unsigned short* gqb = (unsigned short*)(ws);                 // 8 MiB
  unsigned short* gkb = (unsigned short*)(ws + 8388608);       // 8 MiB
  unsigned short* wqb = (unsigned short*)(ws + 16777216);      // 2 MiB
  unsigned short* wkb = (unsigned short*)(ws + 18874368);      // 2 MiB
  unsigned short* qp  = (unsigned short*)(ws + 20971520);      // 8 MiB
  unsigned short* kp  = (unsigned short*)(ws + 29360128);      // 8 MiB
  float2* partials    = (float2*)(ws + 37748736);              // 512 KiB

  hipLaunchKernelGGL(prep_kernel, dim3(1024), dim3(256), 0, stream,
                     gq, gk, WQ, WK, Wmix, gqb, gkb, wqb, wkb);
  hipLaunchKernelGGL(proj_kernel, dim3(8, 16, 2), dim3(512), 0, stream,
                     gqb, gkb, wqb, wkb, qp, kp);
  hipLaunchKernelGGL(score_lse_kernel, dim3(16, 8, 2), dim3(512), 0, stream,
                     qp, kp, partials);
  hipLaunchKernelGGL(finalize_kernel, dim3(16), dim3(256), 0, stream,
                     partials, out);
}

// Round 8
// 131.971 us; speedup vs baseline: 1.0773x; 1.0773x over previous
//
#include <hip/hip_runtime.h>
#include <hip/hip_bf16.h>
#include <math.h>

// Problem constants (AttentionSynapse): B=2, Tq=Tk=2048, E=Eq=Ek=1024, H=16, D=64
#define B_    2
#define TQ    2048
#define TK    2048
#define E_    1024
#define MTOT  4096   // B*TQ

typedef __attribute__((ext_vector_type(8))) short bf16x8;
typedef __attribute__((ext_vector_type(4))) float f32x4;

__device__ __forceinline__ unsigned short f2bf(float x) {
  unsigned int u = __float_as_uint(x);
  u += 0x7fff + ((u >> 16) & 1);      // round-to-nearest-even
  return (unsigned short)(u >> 16);
}

__device__ __forceinline__ void load_lds16(const void* g, void* l) {
  // async global->LDS, 16B/lane; LDS dest = wave-uniform base + lane*16
  __builtin_amdgcn_global_load_lds(
      (const __attribute__((address_space(1))) unsigned int*)g,
      (__attribute__((address_space(3))) unsigned int*)l, 16, 0, 0);
}

#define BARRIER() do { asm volatile("" ::: "memory"); __builtin_amdgcn_s_barrier(); asm volatile("" ::: "memory"); } while (0)
#define WAIT_VM6()   asm volatile("s_waitcnt vmcnt(6)" ::: "memory")
#define WAIT_VM0()   asm volatile("s_waitcnt vmcnt(0)" ::: "memory")

// ---------------------------------------------------------------------------
// T2 swizzle: logical (row, byte o in 0..127) lives at LDS byte
//   row*128 + (o ^ ((row&7)<<4)).
// LDS write is linear (gload_lds: base + tid*16); the GLOBAL source column is
// pre-permuted with the same involutive XOR; ds_read applies the XOR (rule #21).
// ---------------------------------------------------------------------------

// A-tile: 256 rows x 64 cols bf16 (32 KiB), 512 threads x 4 loads.
__device__ __forceinline__ void stage_A(const unsigned short* gsrc, unsigned short* lds,
                                        int tid, int kt) {
  const int r  = tid >> 3;                          // 0..63
  const int c8 = ((tid & 7) ^ (r & 7)) * 8;         // pre-swizzled col (elems)
  const unsigned short* g = gsrc + (size_t)r * E_ + (size_t)kt * 64 + c8;
  unsigned short* l = lds + tid * 8;
#pragma unroll
  for (int i = 0; i < 4; ++i)                       // rows r, r+64, r+128, r+192
    load_lds16(g + (size_t)(64 * i) * E_, l + 4096 * i);
}
// B-tile: 128 rows x 64 cols bf16 (16 KiB), 512 threads x 2 loads.
__device__ __forceinline__ void stage_B(const unsigned short* gsrc, unsigned short* lds,
                                        int tid, int kt) {
  const int r  = tid >> 3;
  const int c8 = ((tid & 7) ^ (r & 7)) * 8;
  const unsigned short* g = gsrc + (size_t)r * E_ + (size_t)kt * 64 + c8;
  unsigned short* l = lds + tid * 8;
#pragma unroll
  for (int i = 0; i < 2; ++i)                       // rows r, r+64
    load_lds16(g + (size_t)(64 * i) * E_, l + 4096 * i);
}

// Swizzled LDS read address (elems): row in tile, o = byte offset in row
#define LDS_AT(base, row, o) ((const bf16x8*)((base) + (((row) * 128 + ((o) ^ (((row) & 7) << 4))) >> 1)))

#define READ_A_ALL()                                                          \
  do {                                                                        \
    _Pragma("unroll") for (int f = 0; f < 4; ++f)                             \
      _Pragma("unroll") for (int ks = 0; ks < 2; ++ks)                        \
        a[f][ks] = *LDS_AT(Ac, wm * 64 + f * 16 + li16, ks * 64 + hi4 * 16);  \
  } while (0)

#define READ_B(g0)                                                            \
  do {                                                                        \
    _Pragma("unroll") for (int g = (g0); g < (g0) + 2; ++g)                   \
      _Pragma("unroll") for (int ks = 0; ks < 2; ++ks)                        \
        b[g][ks] = *LDS_AT(Bc, wn * 64 + g * 16 + li16, ks * 64 + hi4 * 16);  \
  } while (0)

#define MFMA_HALF(g0)                                                         \
  do {                                                                        \
    __builtin_amdgcn_s_setprio(1);                                            \
    _Pragma("unroll") for (int ks = 0; ks < 2; ++ks)                          \
      _Pragma("unroll") for (int f = 0; f < 4; ++f)                           \
        _Pragma("unroll") for (int g = (g0); g < (g0) + 2; ++g)               \
          acc[f][g] = __builtin_amdgcn_mfma_f32_16x16x32_bf16(                \
              a[f][ks], b[g][ks], acc[f][g], 0, 0, 0);                        \
    __builtin_amdgcn_s_setprio(0);                                            \
  } while (0)

// 256x128 tile, BK=64, 8 waves (4M x 2N), per-wave C = 64x64, NT=16 K-tiles.
// BOTH A and B on 3-slot rings: prefetch distance 2 for every load (flight
// ~1.5 tiles > HBM latency), one barrier per tile, counted vmcnt(6).
// Outstanding trace (per thread, new->old) at tile-t end:
//   A(t+2)[4], B(t+2)[2], A(t+1)[4], B(t+1)[2] = 12 -> wait<=6 drains t+1 set.
// Slot safety: stage(t+2) -> slot (t+2)%3; current tile reads t%3, next reads
// (t+1)%3 — never collides. Tile-(t-1) reads of slot (t+2)%3 retired before
// this tile's barrier (reads complete before their MFMA completes).
#define GEMM_PIPELINE()                                                       \
  do {                                                                        \
    stage_B(Bg, Bsl[0], tid, 0); stage_A(Ag, Asl[0], tid, 0);                 \
    stage_B(Bg, Bsl[1], tid, 1); stage_A(Ag, Asl[1], tid, 1);                 \
    WAIT_VM6();    /* drains B0+A0; B1+A1 (6) stay in flight */               \
    int s0 = 0, s2 = 2;   /* t%3, (t+2)%3 */                                  \
    for (int t = 0; t < 16; ++t) {                                            \
      BARRIER();                                                              \
      const unsigned short* Ac = Asl[s0];                                     \
      const unsigned short* Bc = Bsl[s0];                                     \
      /* q0: left C-half */                                                   \
      READ_A_ALL(); READ_B(0);                                                \
      stage_B(Bg, Bsl[s2], tid, (t + 2) & 15);                                \
      MFMA_HALF(0);                                                           \
      /* q1: right C-half */                                                  \
      READ_B(2);                                                              \
      stage_A(Ag, Asl[s2], tid, (t + 2) & 15);                                \
      MFMA_HALF(2);                                                           \
      WAIT_VM6();                                                             \
      s0 = (s0 == 2) ? 0 : s0 + 1;                                            \
      s2 = (s2 == 2) ? 0 : s2 + 1;                                            \
    }                                                                         \
  } while (0)

// ---------------------------------------------------------------------------
// prep: bf16-cast gq, gk, WK; scale WQ rows by Wmix[head] then cast.
// ---------------------------------------------------------------------------
__global__ void prep_kernel(const float* __restrict__ gq, const float* __restrict__ gk,
                            const float* __restrict__ WQ, const float* __restrict__ WK,
                            const float* __restrict__ Wmix,
                            unsigned short* __restrict__ gqb, unsigned short* __restrict__ gkb,
                            unsigned short* __restrict__ wqb, unsigned short* __restrict__ wkb) {
  const int NGQ = (B_ * TQ * E_) / 4;   // 1048576 vec4
  const int NW  = (E_ * E_) / 4;        // 262144 vec4
  const int total = 2 * NGQ + 2 * NW;
  for (int idx = blockIdx.x * blockDim.x + threadIdx.x; idx < total;
       idx += gridDim.x * blockDim.x) {
    const float4* src; unsigned short* dst; int local; float scale = 1.0f;
    if (idx < NGQ)            { src = (const float4*)gq; dst = gqb; local = idx; }
    else if (idx < 2 * NGQ)   { src = (const float4*)gk; dst = gkb; local = idx - NGQ; }
    else if (idx < 2*NGQ+NW)  { src = (const float4*)WQ; dst = wqb; local = idx - 2*NGQ;
                                scale = Wmix[local >> 14]; }   // vec4 idx -> row e = local/256, head = e/64
    else                      { src = (const float4*)WK; dst = wkb; local = idx - 2*NGQ - NW; }
    float4 v = src[local];
    ushort4 o;
    o.x = f2bf(v.x * scale); o.y = f2bf(v.y * scale);
    o.z = f2bf(v.z * scale); o.w = f2bf(v.w * scale);
    ((ushort4*)dst)[local] = o;
  }
}

// ---------------------------------------------------------------------------
// Projection GEMM: C[m,n] = sum_k A[m,k]*W[n,k]. 256x128 tile, 1 block/CU.
// 1-D grid of 256, T1 XCD-rectangle decode: launch id g runs on XCD g&7
// (round-robin dispatch); XCD x covers side = x>>2, mt-rect r = x&3:
// its 32 co-resident blocks span 4 mt x 8 nt = 4*512K + 8*256K = 4 MB = L2.
// ---------------------------------------------------------------------------
__global__ __launch_bounds__(512, 2) void proj_kernel(
    const unsigned short* __restrict__ gqb, const unsigned short* __restrict__ gkb,
    const unsigned short* __restrict__ wqb, const unsigned short* __restrict__ wkb,
    unsigned short* __restrict__ qp, unsigned short* __restrict__ kp) {
  __shared__ __align__(16) unsigned short Asl[3][16384];   // 3 x (256x64)
  __shared__ __align__(16) unsigned short Bsl[3][8192];    // 3 x (128x64)
  const int g_  = blockIdx.x;
  const int xcd = g_ & 7, j = g_ >> 3;      // j in 0..31
  const int side = xcd >> 2, r_ = xcd & 3;
  const int mt = r_ * 4 + (j & 3);          // 0..15
  const int nt = j >> 2;                    // 0..7
  const int m0 = mt * 256, n0 = nt * 128;
  const unsigned short* Ag = (side ? gkb : gqb) + (size_t)m0 * E_;
  const unsigned short* Bg = (side ? wkb : wqb) + (size_t)n0 * E_;
  unsigned short* C        = (side ? kp  : qp);
  const int tid = threadIdx.x, wave = tid >> 6, lane = tid & 63;
  const int wm = wave >> 1, wn = wave & 1, li16 = lane & 15, hi4 = lane >> 4;
  f32x4 acc[4][4] = {};
  bf16x8 a[4][2];
  bf16x8 b[4][2];
  GEMM_PIPELINE();
#pragma unroll
  for (int f = 0; f < 4; ++f)
#pragma unroll
    for (int g = 0; g < 4; ++g)
#pragma unroll
      for (int j2 = 0; j2 < 4; ++j2) {
        int row = m0 + wm * 64 + f * 16 + hi4 * 4 + j2;
        int col = n0 + wn * 64 + g * 16 + li16;
        C[(size_t)row * E_ + col] = f2bf(acc[f][g][j2]);
      }
  WAIT_VM0();   // drain wrapped tail stages before endpgm
}

// ---------------------------------------------------------------------------
// Score GEMM + fused partial logsumexp. 256x128 tile, 1 block/CU.
// 1-D grid of 256, T1 XCD-rectangle decode: XCD x covers batch = x>>2,
// rect r = x&3 -> qt in [(r&1)*4, +4), kt in [(r>>1)*8, +8); its 32 blocks
// span 4 qt-panels (2 MB) + 8 kt-panels (2 MB) = 4 MB = one XCD L2.
// partials stride 16 (kt).
// ---------------------------------------------------------------------------
__global__ __launch_bounds__(512, 2) void score_lse_kernel(
    const unsigned short* __restrict__ qp, const unsigned short* __restrict__ kp,
    float2* __restrict__ partials) {
  __shared__ __align__(16) unsigned short Asl[3][16384];
  __shared__ __align__(16) unsigned short Bsl[3][8192];
  __shared__ float redM[2][256];
  __shared__ float redS[2][256];
  const int g_  = blockIdx.x;
  const int xcd = g_ & 7, j = g_ >> 3;      // j in 0..31
  const int bb = xcd >> 2, r_ = xcd & 3;
  const int qt = (r_ & 1) * 4 + (j & 3);    // 0..7
  const int kt = (r_ >> 1) * 8 + (j >> 2);  // 0..15
  const int m0 = qt * 256, n0 = kt * 128;
  const unsigned short* Ag = qp + (size_t)bb * TQ * E_ + (size_t)m0 * E_;
  const unsigned short* Bg = kp + (size_t)bb * TK * E_ + (size_t)n0 * E_;
  const int tid = threadIdx.x, wave = tid >> 6, lane = tid & 63;
  const int wm = wave >> 1, wn = wave & 1, li16 = lane & 15, hi4 = lane >> 4;
  f32x4 acc[4][4] = {};
  bf16x8 a[4][2];
  bf16x8 b[4][2];
  GEMM_PIPELINE();
  // ---- per-row LSE partial over this block's 128 cols ----
  // lane holds rows wm*64 + f*16 + hi4*4 + j2 ; cols wn*64 + g*16 + li16
#pragma unroll
  for (int f = 0; f < 4; ++f) {
#pragma unroll
    for (int j2 = 0; j2 < 4; ++j2) {
      float m = fmaxf(fmaxf(acc[f][0][j2], acc[f][1][j2]),
                      fmaxf(acc[f][2][j2], acc[f][3][j2]));
#pragma unroll
      for (int msk = 1; msk < 16; msk <<= 1) m = fmaxf(m, __shfl_xor(m, msk, 64));
      float s = 0.f;
#pragma unroll
      for (int g = 0; g < 4; ++g) s += expf(acc[f][g][j2] - m);
#pragma unroll
      for (int msk = 1; msk < 16; msk <<= 1) s += __shfl_xor(s, msk, 64);
      if (li16 == 0) {
        int row = wm * 64 + f * 16 + hi4 * 4 + j2;   // 0..255 unique per (wm,f,hi4,j2)
        redM[wn][row] = m;
        redS[wn][row] = s;
      }
    }
  }
  __syncthreads();   // drains pending tail stages + makes red[] visible
  if (tid < 256) {
    float mA = redM[0][tid], mB = redM[1][tid];
    float M = fmaxf(mA, mB);
    float S = redS[0][tid] * expf(mA - M) + redS[1][tid] * expf(mB - M);
    int qrow = bb * TQ + m0 + tid;
    partials[(size_t)qrow * 16 + kt] = make_float2(M, S);
  }
}

// ---------------------------------------------------------------------------
// finalize: combine 16 (m,s) partials per q-row -> logsumexp
// ---------------------------------------------------------------------------
__global__ void finalize_kernel(const float2* __restrict__ partials, float* __restrict__ out) {
  int r = blockIdx.x * blockDim.x + threadIdx.x;
  if (r >= MTOT) return;
  const float2* p = partials + (size_t)r * 16;
  float M = p[0].x;
#pragma unroll
  for (int i = 1; i < 16; ++i) M = fmaxf(M, p[i].x);
  float S = 0.f;
#pragma unroll
  for (int i = 0; i < 16; ++i) S += p[i].y * expf(p[i].x - M);
  out[r] = logf(S) + M;
}

// ---------------------------------------------------------------------------
extern "C" void kernel_launch(void* const* d_in, const int* in_sizes, int n_in,
                              void* d_out, int out_size, void* d_ws, size_t ws_size,
                              hipStream_t stream) {
  const float* gq   = (const float*)d_in[0];
  const float* gk   = (const float*)d_in[1];
  const float* WQ   = (const float*)d_in[2];
  const float* WK   = (const float*)d_in[3];
  const float* Wmix = (const float*)d_in[4];
  float* out = (float*)d_out;

  char* ws = (char*)d_ws;
  unsigned short* gqb = (unsigned short*)(ws);                 // 8 MiB
  unsigned short* gkb = (unsigned short*)(ws + 8388608);       // 8 MiB
  unsigned short* wqb = (unsigned short*)(ws + 16777216);      // 2 MiB
  unsigned short* wkb = (unsigned short*)(ws + 18874368);      // 2 MiB
  unsigned short* qp  = (unsigned short*)(ws + 20971520);      // 8 MiB
  unsigned short* kp  = (unsigned short*)(ws + 29360128);      // 8 MiB
  float2* partials    = (float2*)(ws + 37748736);              // 512 KiB

  hipLaunchKernelGGL(prep_kernel, dim3(1024), dim3(256), 0, stream,
                     gq, gk, WQ, WK, Wmix, gqb, gkb, wqb, wkb);
  hipLaunchKernelGGL(proj_kernel, dim3(256), dim3(512), 0, stream,
                     gqb, gkb, wqb, wkb, qp, kp);
  hipLaunchKernelGGL(score_lse_kernel, dim3(256), dim3(512), 0, stream,
                     qp, kp, partials);
  hipLaunchKernelGGL(finalize_kernel, dim3(16), dim3(256), 0, stream,
                     partials, out);
}